// Round 4
// baseline (280.951 us; speedup 1.0000x reference)
//
#include <hip/hip_runtime.h>
#include <hip/hip_fp16.h>
#include <math.h>

// AmpNorm via real-input 2D FFT (half spectrum, fp16 intermediate) on MI355X.
// FFT-384 = 12 (register FFT per lane) x 32 (cross-lane shuffle FFT), four-step.
// Row kernels: 1 barrier (output transpose). Col kernels: 2 barriers (tile stage).
// A: [96][384][PADW=208] __half2, w=0..192 valid, 193..207 zero.

#define NFFT   384
#define PADW   208
#define HPLANE (NFFT * PADW)      // 79872
#define PLANE  147456             // 384*384
#define IMGS   96
#define LSTR2  388                // row-kernel LDS line stride (float2)
#define TSTR   17                 // col-kernel LDS tile stride (half2)

__device__ __forceinline__ float2 cmul(float2 a, float2 b) {
    return make_float2(a.x*b.x - a.y*b.y, a.x*b.y + a.y*b.x);
}
__device__ __forceinline__ float2 cadd(float2 a, float2 b) { return make_float2(a.x+b.x, a.y+b.y); }
__device__ __forceinline__ float2 csub(float2 a, float2 b) { return make_float2(a.x-b.x, a.y-b.y); }

// ---- 12-point FFT in registers: z[j] (j=0..11) -> z[k1]. 12 = 3 (outer DFT3) x 4 (inner DFT4).
template<int DIR>
__device__ __forceinline__ void fft12(float2 z[12]) {
    const float dir = (float)DIR;
    const float H = 0.86602540378443864676f;   // sqrt(3)/2
    float2 G[12];                               // G[b*4+ka]
    #pragma unroll
    for (int b = 0; b < 3; ++b) {
        float2 a0 = z[b], a1 = z[b+3], a2 = z[b+6], a3 = z[b+9];
        float2 t0 = cadd(a0, a2), t1 = csub(a0, a2);
        float2 t2 = cadd(a1, a3), t3 = csub(a1, a3);
        G[b*4+0] = cadd(t0, t2);
        G[b*4+1] = make_float2(t1.x + dir*t3.y, t1.y - dir*t3.x);
        G[b*4+2] = csub(t0, t2);
        G[b*4+3] = make_float2(t1.x - dir*t3.y, t1.y + dir*t3.x);
    }
    const float2 W1 = make_float2( H,    -dir*0.5f);
    const float2 W2 = make_float2( 0.5f, -dir*H);
    const float2 W3 = make_float2( 0.0f, -dir);
    const float2 W4 = make_float2(-0.5f, -dir*H);
    const float2 W6 = make_float2(-1.0f,  0.0f);
    G[4+1] = cmul(G[4+1], W1);  G[4+2] = cmul(G[4+2], W2);  G[4+3] = cmul(G[4+3], W3);
    G[8+1] = cmul(G[8+1], W2);  G[8+2] = cmul(G[8+2], W4);  G[8+3] = cmul(G[8+3], W6);
    const float b3 = -dir * H;
    #pragma unroll
    for (int ka = 0; ka < 4; ++ka) {
        float2 g0 = G[ka], g1 = G[4+ka], g2 = G[8+ka];
        float2 t = cadd(g1, g2), d = csub(g1, g2);
        float2 u = make_float2(g0.x - 0.5f*t.x, g0.y - 0.5f*t.y);
        z[ka]   = cadd(g0, t);
        z[ka+4] = make_float2(u.x - b3*d.y, u.y + b3*d.x);
        z[ka+8] = make_float2(u.x + b3*d.y, u.y - b3*d.x);
    }
}

// ---- cross-lane 32-FFT twiddles/signs (per lane l in [0,32)) ----
struct Tw32 { float2 w16, w8, w4, w2; float s16, s8, s4, s2, s1; };

template<int DIR>
__device__ __forceinline__ float2 stage_w(int l, int m) {
    if (l & m) {
        float ph = 3.14159265358979323846f * (float)(l & (m-1)) / (float)m;
        float sv, cv; sincosf(ph, &sv, &cv);
        return make_float2(cv, -(float)DIR * sv);
    }
    return make_float2(1.0f, 0.0f);
}

template<int DIR>
__device__ __forceinline__ Tw32 make_tw32(int l) {
    Tw32 T;
    T.w16 = stage_w<DIR>(l, 16);
    T.w8  = stage_w<DIR>(l, 8);
    T.w4  = stage_w<DIR>(l, 4);
    T.w2  = (l & 2) ? ((l & 1) ? make_float2(0.0f, -(float)DIR) : make_float2(1.0f, 0.0f))
                    : make_float2(1.0f, 0.0f);
    T.s16 = (l & 16) ? -1.0f : 1.0f;
    T.s8  = (l & 8)  ? -1.0f : 1.0f;
    T.s4  = (l & 4)  ? -1.0f : 1.0f;
    T.s2  = (l & 2)  ? -1.0f : 1.0f;
    T.s1  = (l & 1)  ? -1.0f : 1.0f;
    return T;
}

__device__ __forceinline__ float2 bfly(float2 v, int mask, float s, float2 w) {
    float2 p, t;
    p.x = __shfl_xor(v.x, mask, 64);
    p.y = __shfl_xor(v.y, mask, 64);
    t.x = fmaf(s, v.x, p.x);
    t.y = fmaf(s, v.y, p.y);
    return cmul(t, w);
}

// DIF radix-2 32-FFT across lanes; natural input order, output at lane l = X[bitrev5(l)].
__device__ __forceinline__ float2 fft32_slot(float2 v, const Tw32& T) {
    v = bfly(v, 16, T.s16, T.w16);
    v = bfly(v, 8,  T.s8,  T.w8);
    v = bfly(v, 4,  T.s4,  T.w4);
    v = bfly(v, 2,  T.s2,  T.w2);
    float2 p;
    p.x = __shfl_xor(v.x, 1, 64);
    p.y = __shfl_xor(v.y, 1, 64);
    v.x = fmaf(T.s1, v.x, p.x);
    v.y = fmaf(T.s1, v.y, p.y);
    return v;
}

// Full 384-FFT: input z[j] = x[32j + l]; output z[k1] = X[k1 + 12*bitrev5(l)].
template<int DIR>
__device__ __forceinline__ void fft384_reg(float2 z[12], int l) {
    fft12<DIR>(z);
    float ang = (6.28318530717958647692f / 384.0f) * (float)l;
    float sv, cv; sincosf(ang, &sv, &cv);
    float2 w1 = make_float2(cv, -(float)DIR * sv);
    float2 wk = w1;
    z[1] = cmul(z[1], wk);
    #pragma unroll
    for (int k = 2; k < 12; ++k) { wk = cmul(wk, w1); z[k] = cmul(z[k], wk); }
    Tw32 T = make_tw32<DIR>(l);
    #pragma unroll
    for (int k = 0; k < 12; ++k) z[k] = fft32_slot(z[k], T);
}

// ---- K1: forward row FFT (2 real rows packed), Hermitian half-spectrum out (fp16) ----
__global__ __launch_bounds__(256, 5) void k_fft_rows_fwd(const float* __restrict__ x,
                                                         __half2* __restrict__ A) {
    __shared__ float2 lbuf[8 * LSTR2];
    int tid = threadIdx.x, g = tid >> 5, l = tid & 31;
    int img = blockIdx.x / 24, rg = blockIdx.x % 24;
    int pr = rg * 8 + g;                         // row-pair [0,192)
    const float* xa = x + (size_t)img * PLANE + (size_t)(2 * pr) * NFFT;
    const float* xb = xa + NFFT;
    float2 z[12];
    #pragma unroll
    for (int j = 0; j < 12; ++j) z[j] = make_float2(xa[32*j + l], xb[32*j + l]);
    fft384_reg<1>(z, l);
    int r = __brev((unsigned)l) >> 27;
    float2* s = lbuf + g * LSTR2;
    #pragma unroll
    for (int k = 0; k < 12; ++k) s[k + 12*r] = z[k];
    __syncthreads();
    __half2* Aa = A + ((size_t)img * NFFT + 2 * pr) * PADW;
    __half2* Ab = Aa + PADW;
    #pragma unroll
    for (int i = 0; i < 7; ++i) {
        int w = l + 32 * i;
        if (w <= 192) {
            float2 Z  = s[w];
            float2 Zm = s[w == 0 ? 0 : NFFT - w];
            Aa[w] = __floats2half2_rn(0.5f * (Z.x + Zm.x),  0.5f * (Z.y - Zm.y));
            Ab[w] = __floats2half2_rn(0.5f * (Z.y + Zm.y), -0.5f * (Z.x - Zm.x));
        }
    }
    if (l < 15) {
        Aa[193 + l] = __floats2half2_rn(0.0f, 0.0f);
        Ab[193 + l] = __floats2half2_rn(0.0f, 0.0f);
    }
}

// ---- K2: forward column FFT on half spectrum, in place ----
__global__ __launch_bounds__(256, 5) void k_fft_cols_fwd(__half2* __restrict__ A) {
    __shared__ __half2 tile[NFFT * TSTR];
    int tid = threadIdx.x, g = tid >> 5, l = tid & 31;
    int img = blockIdx.x / 13, cg = blockIdx.x % 13;
    int w0 = cg * 16;
    __half2* Ai = A + (size_t)img * HPLANE;
    #pragma unroll
    for (int rr = 0; rr < 24; ++rr) {
        int idx = rr * 256 + tid;
        int h = idx >> 4, wc = idx & 15;
        tile[h * TSTR + wc] = Ai[h * PADW + w0 + wc];
    }
    __syncthreads();
    #pragma unroll
    for (int cc = 0; cc < 2; ++cc) {
        int wc = 2 * g + cc;
        float2 z[12];
        #pragma unroll
        for (int j = 0; j < 12; ++j) z[j] = __half22float2(tile[(l + 32*j) * TSTR + wc]);
        fft384_reg<1>(z, l);
        int r = __brev((unsigned)l) >> 27;
        #pragma unroll
        for (int k = 0; k < 12; ++k)
            tile[(k + 12*r) * TSTR + wc] = __floats2half2_rn(z[k].x, z[k].y);
    }
    __syncthreads();
    #pragma unroll
    for (int rr = 0; rr < 24; ++rr) {
        int idx = rr * 256 + tid;
        int h = idx >> 4, wc = idx & 15;
        Ai[h * PADW + w0 + wc] = tile[h * TSTR + wc];
    }
}

// ---- K3: deterministic sum of running_amp -> flag ----
__global__ __launch_bounds__(256) void k_sum_part(const float* __restrict__ r,
                                                  float* __restrict__ partial) {
    __shared__ float sm[256];
    int t = blockIdx.x * 256 + threadIdx.x;
    sm[threadIdx.x] = r[t];
    __syncthreads();
    for (int s = 128; s > 0; s >>= 1) {
        if (threadIdx.x < s) sm[threadIdx.x] += sm[threadIdx.x + s];
        __syncthreads();
    }
    if (threadIdx.x == 0) partial[blockIdx.x] = sm[0];
}

__global__ __launch_bounds__(256) void k_sum_final(const float* __restrict__ partial,
                                                   float* __restrict__ flag) {
    __shared__ float sm[256];
    float v = 0.0f;
    for (int t = threadIdx.x; t < 1728; t += 256) v += partial[t];
    sm[threadIdx.x] = v;
    __syncthreads();
    for (int s = 128; s > 0; s >>= 1) {
        if (threadIdx.x < s) sm[threadIdx.x] += sm[threadIdx.x + s];
        __syncthreads();
    }
    if (threadIdx.x == 0) flag[0] = sm[0];
}

// ---- K4: batch-mean amplitude (elementwise, pads give 0) ----
__global__ __launch_bounds__(256) void k_amp(const __half2* __restrict__ A,
                                             float* __restrict__ amp) {
    int t = blockIdx.x * 256 + threadIdx.x;      // [0, 3*HPLANE)
    int c  = t / HPLANE;
    int hw = t - c * HPLANE;
    float s = 0.0f;
    #pragma unroll 4
    for (int b = 0; b < 32; ++b) {
        float2 z = __half22float2(A[(size_t)(b * 3 + c) * HPLANE + hw]);
        s += sqrtf(z.x * z.x + z.y * z.y);
    }
    amp[t] = s * (1.0f / 32.0f);
}

// ---- K5: scale (during coalesced tile load) + inverse column FFT ----
__global__ __launch_bounds__(256, 5) void k_ifft_cols_scale(__half2* __restrict__ A,
                                                            const float* __restrict__ ampm,
                                                            const float* __restrict__ running,
                                                            const float* __restrict__ flag) {
    __shared__ __half2 tile[NFFT * TSTR];
    int tid = threadIdx.x, g = tid >> 5, l = tid & 31;
    int img = blockIdx.x / 13, cg = blockIdx.x % 13;
    int w0 = cg * 16;
    int c = img % 3;
    bool adopt = (flag[0] == 0.0f);
    __half2* Ai = A + (size_t)img * HPLANE;
    const float* ampc = ampm + (size_t)c * HPLANE;
    #pragma unroll
    for (int rr = 0; rr < 24; ++rr) {
        int idx = rr * 256 + tid;
        int h = idx >> 4, wc = idx & 15;
        int e = h * PADW + w0 + wc;
        float2 zv = __half22float2(Ai[e]);
        float am = ampc[e];
        float na;
        if (adopt) na = am;
        else {
            int w = w0 + wc;
            int wr = (w < NFFT) ? w : 0;   // EMA branch not taken in bench (running==0)
            na = 0.9f * running[((size_t)c * NFFT + h) * NFFT + wr] + 0.1f * am;
        }
        float mag = sqrtf(zv.x * zv.x + zv.y * zv.y);
        float2 zn;
        if (mag > 0.0f) { float sc = na / mag; zn = make_float2(zv.x * sc, zv.y * sc); }
        else            { zn = make_float2(na, 0.0f); }
        tile[h * TSTR + wc] = __floats2half2_rn(zn.x, zn.y);
    }
    __syncthreads();
    const float inv = 1.0f / (float)NFFT;
    #pragma unroll
    for (int cc = 0; cc < 2; ++cc) {
        int wc = 2 * g + cc;
        float2 z[12];
        #pragma unroll
        for (int j = 0; j < 12; ++j) z[j] = __half22float2(tile[(l + 32*j) * TSTR + wc]);
        fft384_reg<-1>(z, l);
        int r = __brev((unsigned)l) >> 27;
        #pragma unroll
        for (int k = 0; k < 12; ++k)
            tile[(k + 12*r) * TSTR + wc] = __floats2half2_rn(z[k].x * inv, z[k].y * inv);
    }
    __syncthreads();
    #pragma unroll
    for (int rr = 0; rr < 24; ++rr) {
        int idx = rr * 256 + tid;
        int h = idx >> 4, wc = idx & 15;
        Ai[h * PADW + w0 + wc] = tile[h * TSTR + wc];
    }
}

// ---- K6: inverse row FFT (C2R), direct register load from half spectrum ----
__global__ __launch_bounds__(256, 5) void k_ifft_rows_out(const __half2* __restrict__ A,
                                                          float* __restrict__ out) {
    __shared__ float2 lbuf[8 * LSTR2];
    int tid = threadIdx.x, g = tid >> 5, l = tid & 31;
    int img = blockIdx.x / 24, rg = blockIdx.x % 24;
    int pr = rg * 8 + g;
    const __half2* Aa = A + ((size_t)img * NFFT + 2 * pr) * PADW;
    const __half2* Ab = Aa + PADW;
    float2 z[12];
    #pragma unroll
    for (int j = 0; j < 12; ++j) {
        int n = l + 32 * j;
        if (n <= 192) {
            float2 Fa = __half22float2(Aa[n]);
            float2 Fb = __half22float2(Ab[n]);
            z[j] = make_float2(Fa.x - Fb.y, Fa.y + Fb.x);            // Z = Fa + i*Fb
        } else {
            int m2 = NFFT - n;
            float2 Fa = __half22float2(Aa[m2]);
            float2 Fb = __half22float2(Ab[m2]);
            z[j] = make_float2(Fa.x + Fb.y, Fb.x - Fa.y);            // conj(Fa) + i*conj(Fb)
        }
    }
    fft384_reg<-1>(z, l);
    int r = __brev((unsigned)l) >> 27;
    float2* s = lbuf + g * LSTR2;
    #pragma unroll
    for (int k = 0; k < 12; ++k) s[k + 12*r] = z[k];
    __syncthreads();
    const float inv = 1.0f / (float)NFFT;
    float* oa = out + (size_t)img * PLANE + (size_t)(2 * pr) * NFFT;
    float* ob = oa + NFFT;
    #pragma unroll
    for (int i = 0; i < 12; ++i) {
        int col = l + 32 * i;
        float2 v = s[col];
        oa[col] = v.x * inv;
        ob[col] = v.y * inv;
    }
}

extern "C" void kernel_launch(void* const* d_in, const int* in_sizes, int n_in,
                              void* d_out, int out_size, void* d_ws, size_t ws_size,
                              hipStream_t stream) {
    const float* x       = (const float*)d_in[0];
    const float* running = (const float*)d_in[1];
    float* out = (float*)d_out;

    char* ws = (char*)d_ws;
    __half2* A    = (__half2*)ws;                        // 96*79872*4 = 30,670,848 B
    float*   ampm = (float*)(ws + 30670848);             // 3*79872*4 =     958,464 B
    float*   part = (float*)(ws + 30670848 + 958464);    // 1728*4 B
    float*   flag = (float*)(ws + 30670848 + 958464 + 8192);

    k_sum_part<<<1728, 256, 0, stream>>>(running, part);
    k_sum_final<<<1, 256, 0, stream>>>(part, flag);
    k_fft_rows_fwd<<<IMGS * 24, 256, 0, stream>>>(x, A);
    k_fft_cols_fwd<<<IMGS * 13, 256, 0, stream>>>(A);
    k_amp<<<(3 * HPLANE) / 256, 256, 0, stream>>>(A, ampm);
    k_ifft_cols_scale<<<IMGS * 13, 256, 0, stream>>>(A, ampm, running, flag);
    k_ifft_rows_out<<<IMGS * 24, 256, 0, stream>>>(A, out);
}